// Round 2
// baseline (297.654 us; speedup 1.0000x reference)
//
#include <hip/hip_runtime.h>
#include <math.h>

#define NB 4096
#define PAD 2048
#define BLOCK 256
#define V4 (NB / 4 / BLOCK)   // 4 float4-chunks per thread per stream

__device__ __forceinline__ int mirror_idx(int i) {
    // valid for i in [-PAD, NB+PAD-2]; single reflection
    i = ::abs(i);
    return (i < NB) ? i : (2 * (NB - 1) - i);
}

// ws layout: p[0..NB), d[NB..2NB) = lsp - lsn, ws[2NB] = sum(lsn)
// single block; cost negligible (~4096 elems)
__global__ void fbmp_precompute(const float* __restrict__ logits, float* __restrict__ ws) {
    __shared__ float sred[BLOCK / 64];
    float lsnsum = 0.0f;
    for (int j = threadIdx.x; j < NB; j += BLOCK) {
        float x = logits[j];
        double xd = (double)x;
        // keep p bit-identical to round-1 formula (absmax was 0.0)
        float e = (float)exp(-xd);
        float p = 1.0f / (1.0f + e);
        float lsp = (float)(-log1p(exp(-xd)));  // log_sigmoid(x)
        float lsn = (float)(-log1p(exp(xd)));   // log_sigmoid(-x)
        ws[j] = p;
        ws[NB + j] = lsp - lsn;
        lsnsum += lsn;
    }
    #pragma unroll
    for (int off = 32; off > 0; off >>= 1)
        lsnsum += __shfl_down(lsnsum, off, 64);
    const int lane = threadIdx.x & 63;
    const int wid  = threadIdx.x >> 6;
    if (lane == 0) sred[wid] = lsnsum;
    __syncthreads();
    if (threadIdx.x == 0) {
        float t = 0.0f;
        #pragma unroll
        for (int w = 0; w < BLOCK / 64; ++w) t += sred[w];
        ws[2 * NB] = t;
    }
}

__global__ __launch_bounds__(BLOCK) void fbmp_main(
    const float* __restrict__ u, const int* __restrict__ shift,
    const float* __restrict__ ws,
    float* __restrict__ masks, float* __restrict__ logp)
{
    __shared__ float sred[BLOCK / 64];

    const int b = blockIdx.x;
    const int t = threadIdx.x;
    const float* __restrict__ urow = u + (size_t)b * NB;
    const float* __restrict__ p    = ws;
    const float4* __restrict__ u4  = (const float4*)urow;
    const float4* __restrict__ p4  = (const float4*)ws;
    const float4* __restrict__ d4  = (const float4*)(ws + NB);
    const int s = shift[b] - PAD;

    // ---- gather stream: masks[b][k] = (u[b][mirror(k+s)] < p[mirror(k+s)])
    // issue all 32 scalar loads up front for max memory-level parallelism
    float um[4 * V4];
    float pm[4 * V4];
    #pragma unroll
    for (int i = 0; i < V4; ++i) {
        #pragma unroll
        for (int e = 0; e < 4; ++e) {
            int k = 4 * (t + i * BLOCK) + e;
            int j = mirror_idx(k + s);
            um[4 * i + e] = urow[j];
            pm[4 * i + e] = p[j];
        }
    }

    // ---- natural stream: logp partial = sum over j of (u<p) ? d : 0
    float acc = 0.0f;
    #pragma unroll
    for (int i = 0; i < V4; ++i) {
        float4 uv = u4[t + i * BLOCK];
        float4 pv = p4[t + i * BLOCK];
        float4 dv = d4[t + i * BLOCK];
        acc += (uv.x < pv.x ? dv.x : 0.0f)
             + (uv.y < pv.y ? dv.y : 0.0f)
             + (uv.z < pv.z ? dv.z : 0.0f)
             + (uv.w < pv.w ? dv.w : 0.0f);
    }

    // ---- finish gather: compare + coalesced float4 stores (before the barrier)
    float4* __restrict__ m4 = (float4*)(masks + (size_t)b * NB);
    #pragma unroll
    for (int i = 0; i < V4; ++i) {
        float4 o;
        o.x = (um[4 * i + 0] < pm[4 * i + 0]) ? 1.0f : 0.0f;
        o.y = (um[4 * i + 1] < pm[4 * i + 1]) ? 1.0f : 0.0f;
        o.z = (um[4 * i + 2] < pm[4 * i + 2]) ? 1.0f : 0.0f;
        o.w = (um[4 * i + 3] < pm[4 * i + 3]) ? 1.0f : 0.0f;
        m4[t + i * BLOCK] = o;
    }

    // ---- block reduction for logp
    #pragma unroll
    for (int off = 32; off > 0; off >>= 1)
        acc += __shfl_down(acc, off, 64);
    const int lane = t & 63;
    const int wid  = t >> 6;
    if (lane == 0) sred[wid] = acc;
    __syncthreads();
    if (t == 0) {
        float tot = 0.0f;
        #pragma unroll
        for (int w = 0; w < BLOCK / 64; ++w) tot += sred[w];
        logp[b] = tot + ws[2 * NB];
    }
}

extern "C" void kernel_launch(void* const* d_in, const int* in_sizes, int n_in,
                              void* d_out, int out_size, void* d_ws, size_t ws_size,
                              hipStream_t stream) {
    const float* logits = (const float*)d_in[0];
    const float* u      = (const float*)d_in[1];
    const int*   shift  = (const int*)d_in[2];
    const int B = in_sizes[2];

    float* ws    = (float*)d_ws;                    // 2*NB + 1 floats
    float* masks = (float*)d_out;                   // B*NB
    float* logp  = (float*)d_out + (size_t)B * NB;  // B

    fbmp_precompute<<<1, BLOCK, 0, stream>>>(logits, ws);
    fbmp_main<<<B, BLOCK, 0, stream>>>(u, shift, ws, masks, logp);
}

// Round 3
// 247.256 us; speedup vs baseline: 1.2038x; 1.2038x over previous
//
#include <hip/hip_runtime.h>
#include <math.h>

#define NB 4096
#define PAD 2048
#define BLOCK 256
#define V4 (NB / 4 / BLOCK)   // 4 float4-chunks per thread

__device__ __forceinline__ int mirror_idx(int i) {
    // valid for i in [-PAD, NB+PAD-2]; single reflection
    i = ::abs(i);
    return (i < NB) ? i : (2 * (NB - 1) - i);
}

// ws layout: p[0..NB), d[NB..2NB) = lsp - lsn, ws[2NB] = sum(lsn)
__global__ void fbmp_precompute(const float* __restrict__ logits, float* __restrict__ ws) {
    __shared__ float sred[BLOCK / 64];
    float lsnsum = 0.0f;
    for (int j = threadIdx.x; j < NB; j += BLOCK) {
        float x = logits[j];
        double xd = (double)x;
        // p formula bit-matched the reference in rounds 1-2 (absmax 0.0) -- do not touch
        float e = (float)exp(-xd);
        float p = 1.0f / (1.0f + e);
        float lsp = (float)(-log1p(exp(-xd)));  // log_sigmoid(x)
        float lsn = (float)(-log1p(exp(xd)));   // log_sigmoid(-x)
        ws[j] = p;
        ws[NB + j] = lsp - lsn;
        lsnsum += lsn;
    }
    #pragma unroll
    for (int off = 32; off > 0; off >>= 1)
        lsnsum += __shfl_down(lsnsum, off, 64);
    const int lane = threadIdx.x & 63;
    const int wid  = threadIdx.x >> 6;
    if (lane == 0) sred[wid] = lsnsum;
    __syncthreads();
    if (threadIdx.x == 0) {
        float t = 0.0f;
        #pragma unroll
        for (int w = 0; w < BLOCK / 64; ++w) t += sred[w];
        ws[2 * NB] = t;
    }
}

__global__ __launch_bounds__(BLOCK) void fbmp_main(
    const float* __restrict__ u, const int* __restrict__ shift,
    const float* __restrict__ ws,
    float* __restrict__ masks, float* __restrict__ logp)
{
    __shared__ float sg[NB];            // this row's grid bits
    __shared__ float sred[BLOCK / 64];

    const int b = blockIdx.x;
    const int t = threadIdx.x;
    const float4* __restrict__ u4 = (const float4*)(u + (size_t)b * NB);
    const float4* __restrict__ p4 = (const float4*)ws;
    const float4* __restrict__ d4 = (const float4*)(ws + NB);
    const int s = shift[b] - PAD;       // scalar (b is uniform)

    // ---- phase 1: issue ALL loads up front (12 independent float4s -> max MLP)
    float4 uv[V4], pv[V4], dv[V4];
    #pragma unroll
    for (int i = 0; i < V4; ++i) uv[i] = u4[t + i * BLOCK];
    #pragma unroll
    for (int i = 0; i < V4; ++i) pv[i] = p4[t + i * BLOCK];
    #pragma unroll
    for (int i = 0; i < V4; ++i) dv[i] = d4[t + i * BLOCK];

    // grid bits -> LDS (aligned float4 writes), acc in round-2's exact order
    float acc = 0.0f;
    #pragma unroll
    for (int i = 0; i < V4; ++i) {
        bool c0 = uv[i].x < pv[i].x;
        bool c1 = uv[i].y < pv[i].y;
        bool c2 = uv[i].z < pv[i].z;
        bool c3 = uv[i].w < pv[i].w;
        acc += (c0 ? dv[i].x : 0.0f) + (c1 ? dv[i].y : 0.0f)
             + (c2 ? dv[i].z : 0.0f) + (c3 ? dv[i].w : 0.0f);
        float4 g;
        g.x = c0 ? 1.0f : 0.0f;
        g.y = c1 ? 1.0f : 0.0f;
        g.z = c2 ? 1.0f : 0.0f;
        g.w = c3 ? 1.0f : 0.0f;
        ((float4*)sg)[t + i * BLOCK] = g;
    }
    __syncthreads();

    // ---- phase 2: reflect-shift gather from LDS, aligned float4 stores
    float4* __restrict__ m4 = (float4*)(masks + (size_t)b * NB);
    #pragma unroll
    for (int i = 0; i < V4; ++i) {
        const int k = 4 * (t + i * BLOCK) + s;
        float4 o;
        o.x = sg[mirror_idx(k + 0)];
        o.y = sg[mirror_idx(k + 1)];
        o.z = sg[mirror_idx(k + 2)];
        o.w = sg[mirror_idx(k + 3)];
        m4[t + i * BLOCK] = o;
    }

    // ---- block reduction for logp (identical structure to round 2)
    #pragma unroll
    for (int off = 32; off > 0; off >>= 1)
        acc += __shfl_down(acc, off, 64);
    const int lane = t & 63;
    const int wid  = t >> 6;
    if (lane == 0) sred[wid] = acc;
    __syncthreads();
    if (t == 0) {
        float tot = 0.0f;
        #pragma unroll
        for (int w = 0; w < BLOCK / 64; ++w) tot += sred[w];
        logp[b] = tot + ws[2 * NB];
    }
}

extern "C" void kernel_launch(void* const* d_in, const int* in_sizes, int n_in,
                              void* d_out, int out_size, void* d_ws, size_t ws_size,
                              hipStream_t stream) {
    const float* logits = (const float*)d_in[0];
    const float* u      = (const float*)d_in[1];
    const int*   shift  = (const int*)d_in[2];
    const int B = in_sizes[2];

    float* ws    = (float*)d_ws;                    // 2*NB + 1 floats
    float* masks = (float*)d_out;                   // B*NB
    float* logp  = (float*)d_out + (size_t)B * NB;  // B

    fbmp_precompute<<<1, BLOCK, 0, stream>>>(logits, ws);
    fbmp_main<<<B, BLOCK, 0, stream>>>(u, shift, ws, masks, logp);
}